// Round 4
// baseline (75087.439 us; speedup 1.0000x reference)
//
#include <hip/hip_runtime.h>
#include <hip/hip_bf16.h>
#include <math.h>

#define HDIM 1024
#define NTAG 256
#define BSZ 128
#define TLEN 50
#define G3 3072   // 3*HDIM

typedef unsigned long long u64;

// ---- static workspace pool (all f32) ----
constexpr u64 GX_B   = (u64)TLEN*BSZ*G3*4;        // 78,643,200
constexpr u64 SEQ_B  = (u64)TLEN*BSZ*HDIM*4;      // 26,214,400
constexpr u64 HST_B  = (u64)BSZ*HDIM*4;           // 524,288
constexpr u64 OFF_GX   = 0;
constexpr u64 OFF_OF0  = OFF_GX  + GX_B;
constexpr u64 OFF_OB0  = OFF_OF0 + SEQ_B;
constexpr u64 OFF_ENC  = OFF_OB0 + SEQ_B;
constexpr u64 OFF_HZ   = OFF_ENC + SEQ_B;         // 4 zero-init h-state buffers
constexpr u64 OFF_HT   = OFF_HZ  + 4*HST_B;       // 7 scratch h-state buffers
constexpr u64 OFF_GXD1 = OFF_HT  + 7*HST_B;
constexpr u64 OFF_CTX  = OFF_GXD1 + (u64)BSZ*G3*4;
constexpr u64 OFF_CC   = OFF_CTX + HST_B;
constexpr u64 OFF_NLL  = OFF_CC  + HST_B;
constexpr u64 POOL_B   = OFF_NLL + (u64)TLEN*BSZ*4;
// zero region: OF0..end of HZ (of0, ob0, enc, 4 initial h states)
constexpr u64 ZERO_OFF = OFF_OF0;
constexpr u64 ZERO_B   = (OFF_HZ + 4*HST_B) - OFF_OF0;

__device__ __align__(256) unsigned char g_pool[POOL_B];

__device__ __forceinline__ float sigmf(float x){ return 1.f/(1.f+__expf(-x)); }

__global__ __launch_bounds__(256)
void zero_kernel(u64 off, u64 nbytes){
  u64 i = ((u64)blockIdx.x*blockDim.x + threadIdx.x)*16;
  u64 stride = (u64)gridDim.x*blockDim.x*16;
  for (; i<nbytes; i+=stride) *(float4*)(g_pool+off+i) = float4{0.f,0.f,0.f,0.f};
}

#define AM_ENC 0
#define AM_DEC 1
#define AM_CAT 2

// C[T*B, G3] = A[T*B, K] @ W[G3, K]^T + bias ; everything f32
template<int AMODE>
__global__ __launch_bounds__(256)
void gemm_gx(const float* __restrict__ embed,
             u64 a1_off, u64 a2_off,
             const int* __restrict__ ids,
             const float* __restrict__ W,
             const float* __restrict__ bias,
             u64 c_off, int K)
{
  constexpr int TM=128, TN=64, TK=32;
  __shared__ float As[TK][TM+4];
  __shared__ float Ws[TK][TN+4];
  __shared__ int rowid[TM];
  float* C = (float*)(g_pool + c_off);
  const int m0 = blockIdx.x*TM, n0 = blockIdx.y*TN;
  const int tid = threadIdx.x;

  if (AMODE != AM_CAT){
    for (int r=tid; r<TM; r+=256){
      int m = m0+r, t = m/BSZ, b = m%BSZ;
      rowid[r] = (AMODE==AM_ENC) ? ids[b*TLEN+t] : ((t==0)?1:ids[b*TLEN+t-1]);
    }
    __syncthreads();
  }

  const int tm = tid>>4, tn = tid&15;
  float acc[8][4];
  #pragma unroll
  for (int i=0;i<8;i++){ acc[i][0]=0.f;acc[i][1]=0.f;acc[i][2]=0.f;acc[i][3]=0.f; }

  for (int k0=0;k0<K;k0+=TK){
    if (AMODE==AM_CAT){
      const float* Asrc = (const float*)(g_pool + ((k0<HDIM)? a1_off : a2_off));
      int kb = (k0<HDIM)? k0 : k0-HDIM;
      #pragma unroll
      for (int l=tid; l<TM*TK; l+=256){
        int r=l>>5, k=l&31;
        As[k][r] = Asrc[(u64)(m0+r)*HDIM + kb + k];
      }
    } else {
      #pragma unroll
      for (int l=tid; l<TM*TK; l+=256){
        int r=l>>5, k=l&31;
        As[k][r] = embed[(u64)rowid[r]*HDIM + k0 + k];
      }
    }
    #pragma unroll
    for (int l=tid; l<TN*TK; l+=256){
      int n=l>>5, k=l&31;
      Ws[k][n] = W[(u64)(n0+n)*K + k0 + k];
    }
    __syncthreads();
    #pragma unroll 8
    for (int kk=0;kk<TK;kk++){
      float4 a0 = *(const float4*)&As[kk][tm*8];
      float4 a1 = *(const float4*)&As[kk][tm*8+4];
      float4 w  = *(const float4*)&Ws[kk][tn*4];
      float av[8]={a0.x,a0.y,a0.z,a0.w,a1.x,a1.y,a1.z,a1.w};
      float wv[4]={w.x,w.y,w.z,w.w};
      #pragma unroll
      for (int i=0;i<8;i++){
        #pragma unroll
        for (int j=0;j<4;j++) acc[i][j] += av[i]*wv[j];
      }
    }
    __syncthreads();
  }

  float bv[4];
  #pragma unroll
  for (int j=0;j<4;j++) bv[j] = bias[n0+tn*4+j];
  #pragma unroll
  for (int i=0;i<8;i++){
    int m = m0 + tm*8 + i;
    float4 o;
    o.x=acc[i][0]+bv[0]; o.y=acc[i][1]+bv[1]; o.z=acc[i][2]+bv[2]; o.w=acc[i][3]+bv[3];
    *(float4*)&C[(u64)m*G3 + n0 + tn*4] = o;
  }
}

// One GRU step. OUTMODE: 0 none, 1 fwd out[s], 2 bwd out[len-1-s], 3 bwd accumulate
template<bool MASKED, bool BWD, int OUTMODE>
__global__ __launch_bounds__(256)
void gru_step(u64 gx_off, int gx_single,
              u64 hprev_off, u64 hnext_off,
              const float* __restrict__ whh, const float* __restrict__ bhh,
              const int* __restrict__ lengths, u64 out_off, int s)
{
  constexpr int TB=64, TK=32;
  __shared__ float hs[TK][TB+4];
  __shared__ float ws[TK][52];
  const float* gx = (const float*)(g_pool + gx_off);
  const float* hprev = (const float*)(g_pool + hprev_off);
  float* hnext = (float*)(g_pool + hnext_off);
  float* out = (float*)(g_pool + out_off);
  const int j0 = blockIdx.x*16, b0 = blockIdx.y*TB;
  const int tid = threadIdx.x, tj = tid>>4, tb = tid&15;
  float ar[4]={0,0,0,0}, az[4]={0,0,0,0}, an[4]={0,0,0,0};
  for (int k0=0;k0<HDIM;k0+=TK){
    #pragma unroll
    for (int l=tid; l<TB*TK; l+=256){
      int bb=l>>5, k=l&31;
      hs[k][bb] = hprev[(u64)(b0+bb)*HDIM + k0+k];
    }
    #pragma unroll
    for (int l=tid; l<48*TK; l+=256){
      int r=l>>5, k=l&31;
      ws[k][r] = whh[(u64)((r>>4)*HDIM + j0 + (r&15))*HDIM + k0+k];
    }
    __syncthreads();
    #pragma unroll 8
    for (int kk=0;kk<TK;kk++){
      float4 a = *(const float4*)&hs[kk][tb*4];
      float wr = ws[kk][tj], wz = ws[kk][16+tj], wn = ws[kk][32+tj];
      ar[0]+=a.x*wr; ar[1]+=a.y*wr; ar[2]+=a.z*wr; ar[3]+=a.w*wr;
      az[0]+=a.x*wz; az[1]+=a.y*wz; az[2]+=a.z*wz; az[3]+=a.w*wz;
      an[0]+=a.x*wn; an[1]+=a.y*wn; an[2]+=a.z*wn; an[3]+=a.w*wn;
    }
    __syncthreads();
  }
  const int j = j0 + tj;
  const float br = bhh[j], bz = bhh[HDIM+j], bn = bhh[2*HDIM+j];
  #pragma unroll
  for (int i=0;i<4;i++){
    int b = b0 + tb*4 + i;
    bool m = true; int row = s; int len = TLEN;
    if (MASKED){
      len = lengths[b]; m = (s < len);
      if (BWD){ row = len-1-s; if (row < 0) row = 0; }
    }
    const float* g = gx + (gx_single ? (u64)b : ((u64)row*BSZ + b))*G3;
    float xr=g[j], xz=g[HDIM+j], xn=g[2*HDIM+j];
    float hp = hprev[(u64)b*HDIM + j];
    float r = sigmf(xr + ar[i] + br);
    float z = sigmf(xz + az[i] + bz);
    float n = tanhf(xn + r*(an[i] + bn));
    float hv = (1.f - z)*n + z*hp;
    hnext[(u64)b*HDIM + j] = m ? hv : hp;
    if (OUTMODE==1){ if (m) out[((u64)s*BSZ + b)*HDIM + j] = hv; }
    if (OUTMODE==2){ if (m) out[((u64)(len-1-s)*BSZ + b)*HDIM + j] = hv; }
    if (OUTMODE==3){ if (m){ u64 o=((u64)(len-1-s)*BSZ + b)*HDIM + j; out[o] += hv; } }
  }
}

// C[BSZ, N] = act( concat(A1,A2)[BSZ, K1+K2] @ W[N, K1+K2]^T + bias )
template<int ACT>
__global__ __launch_bounds__(256)
void gemm_acts(u64 a1_off, int K1, u64 a2_off, int K2,
               const float* __restrict__ W, const float* __restrict__ bias,
               u64 c_off, int N)
{
  constexpr int TN=64, TB=32, TK=32;
  __shared__ float As[TK][TB+4];
  __shared__ float Ws[TK][TN+4];
  float* C = (float*)(g_pool + c_off);
  const int n0 = blockIdx.x*TN, b0 = blockIdx.y*TB;
  const int tid=threadIdx.x, tn=tid&15, tb=tid>>4;
  const int K = K1+K2;
  float acc[2][4]={{0,0,0,0},{0,0,0,0}};
  for (int k0=0;k0<K;k0+=TK){
    const float* Asrc = (const float*)(g_pool + ((k0<K1)? a1_off : a2_off));
    int kb = (k0<K1)? k0 : k0-K1;
    #pragma unroll
    for (int l=tid; l<TB*TK; l+=256){
      int bb=l>>5, k=l&31;
      As[k][bb] = Asrc[(u64)(b0+bb)*HDIM + kb+k];
    }
    #pragma unroll
    for (int l=tid; l<TN*TK; l+=256){
      int n=l>>5, k=l&31;
      Ws[k][n] = W[(u64)(n0+n)*K + k0+k];
    }
    __syncthreads();
    #pragma unroll 8
    for (int kk=0;kk<TK;kk++){
      float2 a = *(const float2*)&As[kk][tb*2];
      float4 w = *(const float4*)&Ws[kk][tn*4];
      acc[0][0]+=a.x*w.x; acc[0][1]+=a.x*w.y; acc[0][2]+=a.x*w.z; acc[0][3]+=a.x*w.w;
      acc[1][0]+=a.y*w.x; acc[1][1]+=a.y*w.y; acc[1][2]+=a.y*w.z; acc[1][3]+=a.y*w.w;
    }
    __syncthreads();
  }
  #pragma unroll
  for (int i=0;i<2;i++){
    int b = b0 + tb*2 + i;
    #pragma unroll
    for (int jj=0;jj<4;jj++){
      int n = n0 + tn*4 + jj;
      float v = acc[i][jj] + bias[n];
      if (ACT==1) v = tanhf(v);
      C[(u64)b*N + n] = v;
    }
  }
}

__global__ __launch_bounds__(256)
void attn_kernel(u64 h1_off, u64 enc_off, u64 ctx_off)
{
  const float* h1 = (const float*)(g_pool + h1_off);
  const float* enc = (const float*)(g_pool + enc_off);
  float* ctx = (float*)(g_pool + ctx_off);
  const int b = blockIdx.x, tid = threadIdx.x;
  __shared__ float hsm[HDIM];
  __shared__ float sc[TLEN];
  for (int i=tid;i<HDIM;i+=256) hsm[i]=h1[(u64)b*HDIM+i];
  __syncthreads();
  const int w = tid>>6, l = tid&63;
  for (int t=w; t<TLEN; t+=4){
    const float* e = enc + ((u64)t*BSZ + b)*HDIM;
    float s=0.f;
    for (int k=l;k<HDIM;k+=64) s += hsm[k]*e[k];
    #pragma unroll
    for (int off=32;off;off>>=1) s += __shfl_down(s,off);
    if (l==0) sc[t]=s;
  }
  __syncthreads();
  float mx=-1e30f;
  for (int t=0;t<TLEN;t++) mx = fmaxf(mx, sc[t]);
  __syncthreads();
  if (tid<TLEN) sc[tid] = __expf(sc[tid]-mx);
  __syncthreads();
  float sm=0.f;
  for (int t=0;t<TLEN;t++) sm += sc[t];
  const float inv = 1.f/sm;
  for (int k=tid;k<HDIM;k+=256){
    float a=0.f;
    for (int t=0;t<TLEN;t++) a += sc[t]*enc[((u64)t*BSZ+b)*HDIM + k];
    ctx[(u64)b*HDIM + k] = a*inv;
  }
}

__global__ __launch_bounds__(256)
void logits_kernel(u64 cc_off, const float* __restrict__ Wout,
                   const float* __restrict__ bout, const int* __restrict__ tag_ids,
                   float* __restrict__ dout, u64 nll_off, int t)
{
  const float* cc = (const float*)(g_pool + cc_off);
  float* nll = (float*)(g_pool + nll_off);
  const int b = blockIdx.x, tid = threadIdx.x;
  __shared__ float cs[HDIM];
  __shared__ float lg[NTAG];
  for (int i=tid;i<HDIM;i+=256) cs[i]=cc[(u64)b*HDIM+i];
  __syncthreads();
  const int w = tid>>6, l = tid&63;
  for (int v=w; v<NTAG; v+=4){
    const float* wr = Wout + (u64)v*HDIM;
    float s=0.f;
    for (int k=l;k<HDIM;k+=64) s += cs[k]*wr[k];
    #pragma unroll
    for (int off=32;off;off>>=1) s += __shfl_down(s,off);
    if (l==0) lg[v] = s + bout[v];
  }
  __syncthreads();
  float mx=-1e30f;
  for (int v=0;v<NTAG;v++) mx = fmaxf(mx, lg[v]);
  float sm=0.f;
  for (int v=0;v<NTAG;v++) sm += __expf(lg[v]-mx);
  const float lse = mx + __logf(sm);
  dout[((u64)b*TLEN + t)*NTAG + tid] = lg[tid];
  if (tid==0){
    int tag = tag_ids[b*TLEN + t];
    nll[t*BSZ + b] = lse - lg[tag];
  }
}

__global__ __launch_bounds__(256)
void loss_kernel(u64 nll_off, const int* __restrict__ lengths,
                 float* __restrict__ dout)
{
  const float* nll = (const float*)(g_pool + nll_off);
  __shared__ float red[256];
  const int tid = threadIdx.x;
  float s=0.f;
  for (int i=tid;i<TLEN*BSZ;i+=256){
    int t=i/BSZ, b=i%BSZ;
    if (t < lengths[b]) s += nll[i];
  }
  red[tid]=s; __syncthreads();
  for (int o=128;o;o>>=1){ if (tid<o) red[tid]+=red[tid+o]; __syncthreads(); }
  if (tid==0){
    int den=0;
    for (int b=0;b<BSZ;b++) den += lengths[b];
    dout[(u64)BSZ*TLEN*NTAG] = red[0]/(float)den;
  }
}

extern "C" void kernel_launch(void* const* d_in, const int* in_sizes, int n_in,
                              void* d_out, int out_size, void* d_ws, size_t ws_size,
                              hipStream_t stream)
{
  const float* enc_embed = (const float*)d_in[0];
  const float* e0_wih = (const float*)d_in[1];
  const float* e0_whh = (const float*)d_in[2];
  const float* e0_bih = (const float*)d_in[3];
  const float* e0_bhh = (const float*)d_in[4];
  const float* e1_wih = (const float*)d_in[5];
  const float* e1_whh = (const float*)d_in[6];
  const float* e1_bih = (const float*)d_in[7];
  const float* e1_bhh = (const float*)d_in[8];
  const float* dec_embed = (const float*)d_in[9];
  const float* d_wih = (const float*)d_in[10];
  const float* d_whh = (const float*)d_in[11];
  const float* d_bih = (const float*)d_in[12];
  const float* d_bhh = (const float*)d_in[13];
  const float* concat_w = (const float*)d_in[14];
  const float* concat_b = (const float*)d_in[15];
  const float* out_w = (const float*)d_in[16];
  const float* out_b = (const float*)d_in[17];
  const int* input_ids = (const int*)d_in[18];
  const int* tag_ids  = (const int*)d_in[19];
  const int* lengths  = (const int*)d_in[20];
  float* dout = (float*)d_out;

  const u64 HZ0 = OFF_HZ, HZ1 = OFF_HZ + HST_B, HZ2 = OFF_HZ + 2*HST_B, HZ3 = OFF_HZ + 3*HST_B;
  const u64 HT0 = OFF_HT, HT1 = OFF_HT + HST_B, HT2 = OFF_HT + 2*HST_B;
  const u64 D0A = OFF_HT + 3*HST_B, D0B = OFF_HT + 4*HST_B;
  const u64 D1A = OFF_HT + 5*HST_B, D1B = OFF_HT + 6*HST_B;

  zero_kernel<<<2048,256,0,stream>>>(ZERO_OFF, ZERO_B);

  const dim3 gxgrid(TLEN*BSZ/128, G3/64);   // (50,48)
  const dim3 sgrid(HDIM/16, BSZ/64);        // (64,2)

  // ---- encoder layer 0, forward ----
  gemm_gx<AM_ENC><<<gxgrid,256,0,stream>>>(enc_embed,0,0,input_ids,
                                           e0_wih, e0_bih, OFF_GX, HDIM);
  {
    u64 cur = HZ0, nxt = HT0;
    for (int s=0;s<TLEN;s++){
      gru_step<true,false,1><<<sgrid,256,0,stream>>>(OFF_GX,0,cur,nxt,
          e0_whh,e0_bhh,lengths,OFF_OF0,s);
      u64 t2 = nxt; nxt = cur; cur = t2;
    } // 50 steps (even) -> final state at HZ0
  }
  // ---- encoder layer 0, backward ----
  gemm_gx<AM_ENC><<<gxgrid,256,0,stream>>>(enc_embed,0,0,input_ids,
                                           e0_wih + (u64)G3*HDIM, e0_bih + G3, OFF_GX, HDIM);
  {
    u64 cur = HZ1, nxt = HT1;
    for (int s=0;s<TLEN;s++){
      gru_step<true,true,2><<<sgrid,256,0,stream>>>(OFF_GX,0,cur,nxt,
          e0_whh + (u64)G3*HDIM, e0_bhh + G3, lengths, OFF_OB0, s);
      u64 t2 = nxt; nxt = cur; cur = t2;
    } // final state at HZ1
  }
  // ---- encoder layer 1, forward ----
  gemm_gx<AM_CAT><<<gxgrid,256,0,stream>>>(nullptr, OFF_OF0, OFF_OB0, nullptr,
                                           e1_wih, e1_bih, OFF_GX, 2*HDIM);
  {
    u64 cur = HZ2, nxt = HT2;
    for (int s=0;s<TLEN;s++){
      gru_step<true,false,1><<<sgrid,256,0,stream>>>(OFF_GX,0,cur,nxt,
          e1_whh,e1_bhh,lengths,OFF_ENC,s);
      u64 t2 = nxt; nxt = cur; cur = t2;
    }
  }
  // ---- encoder layer 1, backward (accumulate into enc) ----
  gemm_gx<AM_CAT><<<gxgrid,256,0,stream>>>(nullptr, OFF_OF0, OFF_OB0, nullptr,
                                           e1_wih + (u64)G3*2*HDIM, e1_bih + G3, OFF_GX, 2*HDIM);
  {
    u64 cur = HZ3, nxt = HT2;
    for (int s=0;s<TLEN;s++){
      gru_step<true,true,3><<<sgrid,256,0,stream>>>(OFF_GX,0,cur,nxt,
          e1_whh + (u64)G3*HDIM, e1_bhh + G3, lengths, OFF_ENC, s);
      u64 t2 = nxt; nxt = cur; cur = t2;
    }
  }

  // ---- decoder ----
  gemm_gx<AM_DEC><<<gxgrid,256,0,stream>>>(dec_embed,0,0,tag_ids,
                                           d_wih, d_bih, OFF_GX, HDIM);
  {
    u64 h0cur = HZ0;   // decoder h0 init = layer0 fwd final
    u64 h1cur = HZ1;   // decoder h1 init = layer0 bwd final
    for (int t=0;t<TLEN;t++){
      u64 h0nxt = (t&1)? D0B : D0A;
      u64 h1nxt = (t&1)? D1B : D1A;
      gru_step<false,false,0><<<sgrid,256,0,stream>>>(OFF_GX,0,h0cur,h0nxt,
          d_whh, d_bhh, nullptr, 0, t);
      gemm_acts<0><<<dim3(G3/64,4),256,0,stream>>>(h0nxt, HDIM, 0, 0,
          d_wih + (u64)G3*HDIM, d_bih + G3, OFF_GXD1, G3);
      gru_step<false,false,0><<<sgrid,256,0,stream>>>(OFF_GXD1,1,h1cur,h1nxt,
          d_whh + (u64)G3*HDIM, d_bhh + G3, nullptr, 0, t);
      attn_kernel<<<BSZ,256,0,stream>>>(h1nxt, OFF_ENC, OFF_CTX);
      gemm_acts<1><<<dim3(HDIM/64,4),256,0,stream>>>(h1nxt, HDIM, OFF_CTX, HDIM,
          concat_w, concat_b, OFF_CC, HDIM);
      logits_kernel<<<BSZ,256,0,stream>>>(OFF_CC, out_w, out_b, tag_ids, dout, OFF_NLL, t);
      h0cur = h0nxt; h1cur = h1nxt;
    }
  }
  loss_kernel<<<1,256,0,stream>>>(OFF_NLL, lengths, dout);
}